// Round 9
// baseline (631.301 us; speedup 1.0000x reference)
//
#include <hip/hip_runtime.h>
#include <math.h>

#define BB 8
#define LL 2048
#define DMODEL 128
#define NHEAD 4
#define DHEAD 32
#define DIN 256
#define DSTATE 16
#define NLAYERS 6
#define BLROWS (BB*LL)   // 16384
#define NCHUNK 32
#define CH 64            // scan chunk length

typedef __attribute__((ext_vector_type(8))) short short8;
typedef __attribute__((ext_vector_type(4))) float f32x4;

static __device__ __forceinline__ unsigned cvt_pk_bf16(float a, float b) {
    unsigned r;
    asm volatile("v_cvt_pk_bf16_f32 %0, %1, %2" : "=v"(r) : "v"(a), "v"(b));
    return r;
}

// ---------------- weight fp32 -> bf16 preconversion ----------------
__global__ __launch_bounds__(256) void wcvt_k(
    const float* __restrict__ src, ushort* __restrict__ dst, int n4)
{
    int i = blockIdx.x * 256 + threadIdx.x;
    if (i < n4) {
        float4 v = ((const float4*)src)[i];
        uint2 pw; pw.x = cvt_pk_bf16(v.x, v.y); pw.y = cvt_pk_bf16(v.z, v.w);
        ((uint2*)dst)[i] = pw;
    }
}

// ---------------- mlp1 + positional encoding ----------------
__global__ __launch_bounds__(256) void mlp1_pe_k(
    const float* __restrict__ x, const float* __restrict__ w,
    const float* __restrict__ b, float* __restrict__ h)
{
    int idx = blockIdx.x * 256 + threadIdx.x;   // over BLROWS*128
    int d   = idx & 127;
    int row = idx >> 7;
    int pos = row & (LL - 1);
    float v = x[row] * w[d] + b[d];
    int j2 = (d >> 1) * 2;
    float dv = expf((float)j2 * -0.07195578415603638f);
    float ang = (float)pos * dv;
    v += (d & 1) ? cosf(ang) : sinf(ang);
    h[idx] = v;
}

// ---------------- qkv GEMM: bf16 out, q pre-scaled: C16[M,384] ----------------
#define QSCALE (0.17677669529663687f * 1.4426950408889634f)   // 1/sqrt(32) * log2(e)
__global__ __launch_bounds__(256) void gemm_qkv_k(
    const float* __restrict__ A, const ushort* __restrict__ W16,
    const float* __restrict__ bias, ushort* __restrict__ C16)
{
    __shared__ __align__(16) short As[64][136];
    __shared__ __align__(16) short Ws[128][136];
    int tid = threadIdx.x;
    int w = tid >> 6, lane = tid & 63, lg = lane >> 4, lr = lane & 15;
    int row0 = blockIdx.y * 64, col0 = blockIdx.x * 128;

    const float* Ab = A + (size_t)row0 * 128;
    #pragma unroll
    for (int p = 0; p < 8; ++p) {
        int off = p * 1024 + tid * 4;
        float4 v = *(const float4*)(Ab + off);
        uint2 pw; pw.x = cvt_pk_bf16(v.x, v.y); pw.y = cvt_pk_bf16(v.z, v.w);
        *(uint2*)&As[off >> 7][off & 127] = pw;
    }
    const ushort* Wb = W16 + (size_t)col0 * 128;
    #pragma unroll
    for (int p = 0; p < 8; ++p) {
        int off = p * 2048 + tid * 8;
        short8 v = *(const short8*)(Wb + off);
        *(short8*)&Ws[off >> 7][off & 127] = v;
    }
    __syncthreads();

    short8 af[4];
    #pragma unroll
    for (int kk = 0; kk < 4; ++kk)
        af[kk] = *(short8*)&As[w * 16 + lr][kk * 32 + lg * 8];
    f32x4 acc[8];
    #pragma unroll
    for (int n = 0; n < 8; ++n) acc[n] = (f32x4){0.f, 0.f, 0.f, 0.f};
    #pragma unroll
    for (int n = 0; n < 8; ++n)
        #pragma unroll
        for (int kk = 0; kk < 4; ++kk) {
            short8 bf = *(short8*)&Ws[n * 16 + lr][kk * 32 + lg * 8];
            acc[n] = __builtin_amdgcn_mfma_f32_16x16x32_bf16(af[kk], bf, acc[n], 0, 0, 0);
        }
    float qs = (blockIdx.x == 0) ? QSCALE : 1.f;
    #pragma unroll
    for (int n = 0; n < 8; ++n) {
        int col = col0 + n * 16 + lr;
        float bv = bias[col];
        #pragma unroll
        for (int j = 0; j < 4; ++j) {
            int row = row0 + w * 16 + lg * 4 + j;
            float v = (acc[n][j] + bv) * qs;
            C16[(size_t)row * 384 + col] = (ushort)cvt_pk_bf16(v, v);
        }
    }
}

// ---------------- bf16 MFMA GEMM (in_proj): C[M,N] = A[M,128] @ W[N,128]^T ----------------
__global__ __launch_bounds__(256) void gemm_bf16_k(
    const float* __restrict__ A, const ushort* __restrict__ W16,
    float* __restrict__ C, int N)
{
    __shared__ __align__(16) short As[64][136];
    __shared__ __align__(16) short Ws[128][136];
    int tid = threadIdx.x;
    int w = tid >> 6, lane = tid & 63, lg = lane >> 4, lr = lane & 15;
    int row0 = blockIdx.y * 64, col0 = blockIdx.x * 128;

    const float* Ab = A + (size_t)row0 * 128;
    #pragma unroll
    for (int p = 0; p < 8; ++p) {
        int off = p * 1024 + tid * 4;
        float4 v = *(const float4*)(Ab + off);
        uint2 pw; pw.x = cvt_pk_bf16(v.x, v.y); pw.y = cvt_pk_bf16(v.z, v.w);
        *(uint2*)&As[off >> 7][off & 127] = pw;
    }
    const ushort* Wb = W16 + (size_t)col0 * 128;
    #pragma unroll
    for (int p = 0; p < 8; ++p) {
        int off = p * 2048 + tid * 8;
        short8 v = *(const short8*)(Wb + off);
        *(short8*)&Ws[off >> 7][off & 127] = v;
    }
    __syncthreads();

    short8 af[4];
    #pragma unroll
    for (int kk = 0; kk < 4; ++kk)
        af[kk] = *(short8*)&As[w * 16 + lr][kk * 32 + lg * 8];
    f32x4 acc[8];
    #pragma unroll
    for (int n = 0; n < 8; ++n) acc[n] = (f32x4){0.f, 0.f, 0.f, 0.f};
    #pragma unroll
    for (int n = 0; n < 8; ++n)
        #pragma unroll
        for (int kk = 0; kk < 4; ++kk) {
            short8 bf = *(short8*)&Ws[n * 16 + lr][kk * 32 + lg * 8];
            acc[n] = __builtin_amdgcn_mfma_f32_16x16x32_bf16(af[kk], bf, acc[n], 0, 0, 0);
        }
    #pragma unroll
    for (int n = 0; n < 8; ++n) {
        int col = col0 + n * 16 + lr;
        #pragma unroll
        for (int j = 0; j < 4; ++j) {
            int row = row0 + w * 16 + lg * 4 + j;
            C[(size_t)row * N + col] = acc[n][j];
        }
    }
}

// ---------------- fused GEMM(N=128) + residual + LayerNorm (A bf16, W bf16) ----------------
__global__ __launch_bounds__(256) void gemm_ln_k(
    const ushort* __restrict__ A16, const ushort* __restrict__ W16,
    const float* __restrict__ bias, float* __restrict__ h,
    const float* __restrict__ ls, const float* __restrict__ lb)
{
    __shared__ __align__(16) short As[64][136];
    __shared__ __align__(16) short Ws[128][136];
    int tid = threadIdx.x;
    int w = tid >> 6, lane = tid & 63, lg = lane >> 4, lr = lane & 15;
    int row0 = blockIdx.x * 64;

    const ushort* Ab = A16 + (size_t)row0 * 128;
    #pragma unroll
    for (int p = 0; p < 4; ++p) {
        int off = p * 2048 + tid * 8;
        short8 v = *(const short8*)(Ab + off);
        *(short8*)&As[off >> 7][off & 127] = v;
    }
    #pragma unroll
    for (int p = 0; p < 8; ++p) {
        int off = p * 2048 + tid * 8;
        short8 v = *(const short8*)(W16 + off);
        *(short8*)&Ws[off >> 7][off & 127] = v;
    }
    __syncthreads();

    short8 af[4];
    #pragma unroll
    for (int kk = 0; kk < 4; ++kk)
        af[kk] = *(short8*)&As[w * 16 + lr][kk * 32 + lg * 8];
    f32x4 acc[8];
    #pragma unroll
    for (int n = 0; n < 8; ++n) acc[n] = (f32x4){0.f, 0.f, 0.f, 0.f};
    #pragma unroll
    for (int n = 0; n < 8; ++n)
        #pragma unroll
        for (int kk = 0; kk < 4; ++kk) {
            short8 bf = *(short8*)&Ws[n * 16 + lr][kk * 32 + lg * 8];
            acc[n] = __builtin_amdgcn_mfma_f32_16x16x32_bf16(af[kk], bf, acc[n], 0, 0, 0);
        }

    float bv[8], lsv[8], lbv[8];
    #pragma unroll
    for (int n = 0; n < 8; ++n) {
        int col = n * 16 + lr;
        bv[n] = bias[col]; lsv[n] = ls[col]; lbv[n] = lb[col];
    }
    #pragma unroll
    for (int j = 0; j < 4; ++j) {
        int row = row0 + w * 16 + lg * 4 + j;
        float xv[8]; float sum = 0.f;
        #pragma unroll
        for (int n = 0; n < 8; ++n) {
            xv[n] = acc[n][j] + bv[n] + h[(size_t)row * 128 + n * 16 + lr];
            sum += xv[n];
        }
        sum += __shfl_xor(sum, 1); sum += __shfl_xor(sum, 2);
        sum += __shfl_xor(sum, 4); sum += __shfl_xor(sum, 8);
        float mean = sum * (1.f / 128.f);
        float vs = 0.f;
        #pragma unroll
        for (int n = 0; n < 8; ++n) { float dd = xv[n] - mean; vs += dd * dd; }
        vs += __shfl_xor(vs, 1); vs += __shfl_xor(vs, 2);
        vs += __shfl_xor(vs, 4); vs += __shfl_xor(vs, 8);
        float inv = rsqrtf(vs * (1.f / 128.f) + 1e-5f);
        #pragma unroll
        for (int n = 0; n < 8; ++n)
            h[(size_t)row * 128 + n * 16 + lr] = (xv[n] - mean) * inv * lsv[n] + lbv[n];
    }
}

// ---------------- fused FFW (w1+relu+w2) + residual + LayerNorm (W bf16) ----------------
__global__ __launch_bounds__(256) void ffw_ln_k(
    float* __restrict__ h, const ushort* __restrict__ W1, const float* __restrict__ b1,
    const ushort* __restrict__ W2, const float* __restrict__ b2,
    const float* __restrict__ ls, const float* __restrict__ lb)
{
    __shared__ __align__(16) short As[64][136];
    __shared__ __align__(16) short Ws[128][136];
    int tid = threadIdx.x;
    int w = tid >> 6, lane = tid & 63, lg = lane >> 4, lr = lane & 15;
    int row0 = blockIdx.x * 64;

    const float* Ab = h + (size_t)row0 * 128;
    #pragma unroll
    for (int p = 0; p < 8; ++p) {
        int off = p * 1024 + tid * 4;
        float4 v = *(const float4*)(Ab + off);
        uint2 pw; pw.x = cvt_pk_bf16(v.x, v.y); pw.y = cvt_pk_bf16(v.z, v.w);
        *(uint2*)&As[off >> 7][off & 127] = pw;
    }
    #pragma unroll
    for (int p = 0; p < 8; ++p) {
        int off = p * 2048 + tid * 8;
        short8 v = *(const short8*)(W1 + off);
        *(short8*)&Ws[off >> 7][off & 127] = v;
    }
    __syncthreads();

    short8 af[4];
    #pragma unroll
    for (int kk = 0; kk < 4; ++kk)
        af[kk] = *(short8*)&As[w * 16 + lr][kk * 32 + lg * 8];
    f32x4 acc[8];
    #pragma unroll
    for (int n = 0; n < 8; ++n) acc[n] = (f32x4){0.f, 0.f, 0.f, 0.f};
    #pragma unroll
    for (int n = 0; n < 8; ++n)
        #pragma unroll
        for (int kk = 0; kk < 4; ++kk) {
            short8 bf = *(short8*)&Ws[n * 16 + lr][kk * 32 + lg * 8];
            acc[n] = __builtin_amdgcn_mfma_f32_16x16x32_bf16(af[kk], bf, acc[n], 0, 0, 0);
        }
    __syncthreads();

    {
        float b1v[8];
        #pragma unroll
        for (int n = 0; n < 8; ++n) b1v[n] = b1[n * 16 + lr];
        #pragma unroll
        for (int n = 0; n < 8; ++n) {
            #pragma unroll
            for (int j = 0; j < 4; ++j) {
                float hv = fmaxf(acc[n][j] + b1v[n], 0.f);
                As[w * 16 + lg * 4 + j][n * 16 + lr] = (short)cvt_pk_bf16(hv, hv);
            }
        }
    }
    #pragma unroll
    for (int p = 0; p < 8; ++p) {
        int off = p * 2048 + tid * 8;
        short8 v = *(const short8*)(W2 + off);
        *(short8*)&Ws[off >> 7][off & 127] = v;
    }
    __syncthreads();

    #pragma unroll
    for (int kk = 0; kk < 4; ++kk)
        af[kk] = *(short8*)&As[w * 16 + lr][kk * 32 + lg * 8];
    #pragma unroll
    for (int n = 0; n < 8; ++n) acc[n] = (f32x4){0.f, 0.f, 0.f, 0.f};
    #pragma unroll
    for (int n = 0; n < 8; ++n)
        #pragma unroll
        for (int kk = 0; kk < 4; ++kk) {
            short8 bf = *(short8*)&Ws[n * 16 + lr][kk * 32 + lg * 8];
            acc[n] = __builtin_amdgcn_mfma_f32_16x16x32_bf16(af[kk], bf, acc[n], 0, 0, 0);
        }

    float bv[8], lsv[8], lbv[8];
    #pragma unroll
    for (int n = 0; n < 8; ++n) {
        int col = n * 16 + lr;
        bv[n] = b2[col]; lsv[n] = ls[col]; lbv[n] = lb[col];
    }
    #pragma unroll
    for (int j = 0; j < 4; ++j) {
        int row = row0 + w * 16 + lg * 4 + j;
        float xv[8]; float sum = 0.f;
        #pragma unroll
        for (int n = 0; n < 8; ++n) {
            xv[n] = acc[n][j] + bv[n] + h[(size_t)row * 128 + n * 16 + lr];
            sum += xv[n];
        }
        sum += __shfl_xor(sum, 1); sum += __shfl_xor(sum, 2);
        sum += __shfl_xor(sum, 4); sum += __shfl_xor(sum, 8);
        float mean = sum * (1.f / 128.f);
        float vs = 0.f;
        #pragma unroll
        for (int n = 0; n < 8; ++n) { float dd = xv[n] - mean; vs += dd * dd; }
        vs += __shfl_xor(vs, 1); vs += __shfl_xor(vs, 2);
        vs += __shfl_xor(vs, 4); vs += __shfl_xor(vs, 8);
        float inv = rsqrtf(vs * (1.f / 128.f) + 1e-5f);
        #pragma unroll
        for (int n = 0; n < 8; ++n)
            h[(size_t)row * 128 + n * 16 + lr] = (xv[n] - mean) * inv * lsv[n] + lbv[n];
    }
}

// ---------------- flash-split attention: partial over half the keys ----------------
// grid 2048: bits {half, hd[1:0], qt[4:0], b[2:0]}. 256 thr = 4 waves x 16 q.
// Writes fp32 partial O (64q x 32d) + l per q to workspace; no-max softmax
// makes partials additive across halves.
__global__ __launch_bounds__(256) void attn_part_k(
    const ushort* __restrict__ qkv, float* __restrict__ Opart,
    float* __restrict__ lpart)
{
    __shared__ __align__(16) short Ks[64][40];     // [key][feat]
    __shared__ __align__(16) short Vt[32][72];     // [d][key]
    __shared__ __align__(16) short Pl[4][16][72];  // per-wave P[q][key]

    int bid = blockIdx.x;
    int b    = bid & 7;
    int qt   = (bid >> 3) & 31;
    int hd   = (bid >> 8) & 3;
    int half = bid >> 10;
    int tid  = threadIdx.x;
    int wave = tid >> 6;
    int lane = tid & 63;
    int lg = lane >> 4, lr = lane & 15;

    const ushort* base = qkv + (size_t)b * LL * 384;
    int qr0 = qt * 64 + wave * 16;
    int kt0 = half * 1024;

    short8 qf = *(const short8*)(base + (size_t)(qr0 + lr) * 384 + hd * 32 + lg * 8);

    // staging addresses (tile 0 of this half)
    int kr = tid >> 2, ksg = (tid & 3) * 8;          // K: row, feat seg
    int k2 = (tid & 31) * 2, d0 = (tid >> 5) * 4;    // V: key pair, d seg
    const ushort* kptr = base + (size_t)(kt0 + kr) * 384 + 128 + hd * 32 + ksg;
    const ushort* vptr = base + (size_t)(kt0 + k2) * 384 + 256 + hd * 32 + d0;

    short8 kreg = *(const short8*)kptr;
    uint2 va  = *(const uint2*)vptr;
    uint2 vbr = *(const uint2*)(vptr + 384);

    f32x4 Of[2] = {};
    f32x4 Ol = {};
    const f32x4 zero4 = {0.f, 0.f, 0.f, 0.f};
    short8 ones;
    #pragma unroll
    for (int e = 0; e < 8; ++e) ones[e] = (short)0x3F80;   // bf16 1.0

    #pragma unroll 1
    for (int t = 0; t < 16; ++t) {
        __syncthreads();
        *(short8*)&Ks[kr][ksg] = kreg;
        {
            uint w0 = (va.x & 0xFFFFu) | (vbr.x << 16);
            uint w1 = (va.x >> 16)     | (vbr.x & 0xFFFF0000u);
            uint w2 = (va.y & 0xFFFFu) | (vbr.y << 16);
            uint w3 = (va.y >> 16)     | (vbr.y & 0xFFFF0000u);
            *(uint*)&Vt[d0 + 0][k2] = w0;
            *(uint*)&Vt[d0 + 1][k2] = w1;
            *(uint*)&Vt[d0 + 2][k2] = w2;
            *(uint*)&Vt[d0 + 3][k2] = w3;
        }
        __syncthreads();

        if (t < 15) {
            size_t off = (size_t)(t + 1) * 64 * 384;
            kreg = *(const short8*)(kptr + off);
            va   = *(const uint2*)(vptr + off);
            vbr  = *(const uint2*)(vptr + off + 384);
        }

        // S^T = K Q^T : lane holds S[key=n*16+lg*4+j][q=lr] (log2-scaled)
        f32x4 S[4];
        #pragma unroll
        for (int n = 0; n < 4; ++n) {
            short8 kf = *(short8*)&Ks[n * 16 + lr][lg * 8];
            S[n] = __builtin_amdgcn_mfma_f32_16x16x32_bf16(kf, qf, zero4, 0, 0, 0);
        }

        #pragma unroll
        for (int n = 0; n < 4; ++n) {
            float p0 = exp2f(S[n][0]);
            float p1 = exp2f(S[n][1]);
            float p2 = exp2f(S[n][2]);
            float p3 = exp2f(S[n][3]);
            uint2 pw; pw.x = cvt_pk_bf16(p0, p1); pw.y = cvt_pk_bf16(p2, p3);
            *(uint2*)&Pl[wave][lr][n * 16 + lg * 4] = pw;
        }
        asm volatile("s_waitcnt lgkmcnt(0)" ::: "memory");
        __builtin_amdgcn_sched_barrier(0);

        #pragma unroll
        for (int kb = 0; kb < 2; ++kb) {
            short8 pa = *(short8*)&Pl[wave][lr][kb * 32 + lg * 8];
            Ol = __builtin_amdgcn_mfma_f32_16x16x32_bf16(pa, ones, Ol, 0, 0, 0);
            #pragma unroll
            for (int dt2 = 0; dt2 < 2; ++dt2) {
                short8 vb = *(short8*)&Vt[dt2 * 16 + lr][kb * 32 + lg * 8];
                Of[dt2] = __builtin_amdgcn_mfma_f32_16x16x32_bf16(pa, vb, Of[dt2], 0, 0, 0);
            }
        }
    }

    // write partials: Opart[bid][ql][32], lpart[bid][ql]
    #pragma unroll
    for (int j = 0; j < 4; ++j) {
        int ql = wave * 16 + lg * 4 + j;
        size_t ob = ((size_t)bid * 64 + ql) * 32;
        Opart[ob + lr]      = Of[0][j];
        Opart[ob + 16 + lr] = Of[1][j];
        if (lr == 0) lpart[(size_t)bid * 64 + ql] = Ol[j];
    }
}

// ---------------- attention merge: o = (O0+O1)/(l0+l1), bf16 out ----------------
__global__ __launch_bounds__(256) void attn_merge_k(
    const float* __restrict__ Opart, const float* __restrict__ lpart,
    ushort* __restrict__ o)
{
    int idx = blockIdx.x * 256 + threadIdx.x;   // over BLROWS*128
    int d   = idx & 127;
    int row = idx >> 7;            // b*2048 + q
    int b = row >> 11, q = row & 2047;
    int hd = d >> 5, dl = d & 31;
    int qt = q >> 6, ql = q & 63;
    int bid0 = (hd * 32 + qt) * 8 + b;
    int bid1 = bid0 + 1024;
    float O0 = Opart[((size_t)bid0 * 64 + ql) * 32 + dl];
    float O1 = Opart[((size_t)bid1 * 64 + ql) * 32 + dl];
    float l0 = lpart[(size_t)bid0 * 64 + ql];
    float l1 = lpart[(size_t)bid1 * 64 + ql];
    float v = (O0 + O1) / (l0 + l1);
    o[idx] = (ushort)cvt_pk_bf16(v, v);
}

// ---------------- x_proj bf16 MFMA: dbc[M,40] = xm[M,256] @ W[40,256]^T ----------------
__global__ __launch_bounds__(256) void xproj_bf16_k(
    const float* __restrict__ A, const ushort* __restrict__ W16,
    float* __restrict__ C)
{
    __shared__ __align__(16) short As[64][264];
    __shared__ __align__(16) short Ws[48][264];
    int tid = threadIdx.x;
    int w = tid >> 6, lane = tid & 63, lg = lane >> 4, lr = lane & 15;
    int row0 = blockIdx.x * 64;

    const float* Ab = A + (size_t)row0 * 256;
    #pragma unroll
    for (int p = 0; p < 16; ++p) {
        int off = p * 1024 + tid * 4;           // over 64x256
        float4 v = *(const float4*)(Ab + off);
        uint2 pw; pw.x = cvt_pk_bf16(v.x, v.y); pw.y = cvt_pk_bf16(v.z, v.w);
        *(uint2*)&As[off >> 8][off & 255] = pw;
    }
    #pragma unroll
    for (int p = 0; p < 6; ++p) {
        int off = p * 2048 + tid * 8;           // over 48x256 shorts
        int r = off >> 8, c = off & 255;
        short8 v = {};
        if (r < 40) v = *(const short8*)(W16 + (size_t)r * 256 + c);
        *(short8*)&Ws[r][c] = v;
    }
    __syncthreads();

    short8 af[8];
    #pragma unroll
    for (int kk = 0; kk < 8; ++kk)
        af[kk] = *(short8*)&As[w * 16 + lr][kk * 32 + lg * 8];

    f32x4 acc[3];
    #pragma unroll
    for (int n = 0; n < 3; ++n) acc[n] = (f32x4){0.f, 0.f, 0.f, 0.f};
    #pragma unroll
    for (int n = 0; n < 3; ++n)
        #pragma unroll
        for (int kk = 0; kk < 8; ++kk) {
            short8 bf = *(short8*)&Ws[n * 16 + lr][kk * 32 + lg * 8];
            acc[n] = __builtin_amdgcn_mfma_f32_16x16x32_bf16(af[kk], bf, acc[n], 0, 0, 0);
        }
    #pragma unroll
    for (int n = 0; n < 3; ++n) {
        int col = n * 16 + lr;
        if (col < 40) {
            #pragma unroll
            for (int j = 0; j < 4; ++j) {
                int row = row0 + w * 16 + lg * 4 + j;
                C[(size_t)row * 40 + col] = acc[n][j];
            }
        }
    }
}

// ---------------- causal depthwise conv(4) + silu ----------------
__global__ __launch_bounds__(256) void conv_silu_k(
    const float* __restrict__ xz, const float* __restrict__ cw,
    const float* __restrict__ cb, float* __restrict__ xm)
{
    int idx = blockIdx.x * 256 + threadIdx.x;
    int d   = idx & 255;
    int row = idx >> 8;
    int l   = row & (LL - 1);
    float a = cb[d];
    #pragma unroll
    for (int t = 0; t < 4; ++t) {
        int ll = l - 3 + t;
        if (ll >= 0) a += cw[d * 4 + t] * xz[(size_t)(row - 3 + t) * 512 + d];
    }
    float sg = 1.f / (1.f + expf(-a));
    xm[idx] = a * sg;
}

// ---------------- dt = softplus(dbc[:, :8] @ dt_w^T + dt_b), 4 rows/block ----------------
__global__ __launch_bounds__(256) void dtproj_k(
    const float* __restrict__ dbc, const float* __restrict__ w,
    const float* __restrict__ bias, float* __restrict__ dt)
{
    int row0 = blockIdx.x * 4, n = threadIdx.x;
    __shared__ float dv[4][8];
    if (n < 32) dv[n >> 3][n & 7] = dbc[(size_t)(row0 + (n >> 3)) * 40 + (n & 7)];
    __syncthreads();
    float bv = bias[n];
    float wv[8];
    #pragma unroll
    for (int k = 0; k < 8; ++k) wv[k] = w[n * 8 + k];
    #pragma unroll
    for (int r = 0; r < 4; ++r) {
        float a = bv;
        #pragma unroll
        for (int k = 0; k < 8; ++k) a += dv[r][k] * wv[k];
        float sp = fmaxf(a, 0.f) + log1pf(expf(-fabsf(a)));
        dt[(size_t)(row0 + r) * 256 + n] = sp;
    }
}

// ---------------- scan pass 1 ----------------
__global__ __launch_bounds__(1024) void scan1_k(
    const float* __restrict__ dt, const float* __restrict__ xm,
    const float* __restrict__ dbc, const float* __restrict__ A_log,
    float* __restrict__ Asum, float* __restrict__ Bsum)
{
    int blk = blockIdx.x;             // b*32 + c
    int c = blk & 31, b = blk >> 5;
    int tid = threadIdx.x;
    int d = tid >> 2, sq = tid & 3;   // s = sq*4 + k
    float4 Av4 = *(const float4*)(A_log + d * 16 + sq * 4);
    float Av2[4];
    Av2[0] = -expf(Av4.x) * 1.4426950408889634f;
    Av2[1] = -expf(Av4.y) * 1.4426950408889634f;
    Av2[2] = -expf(Av4.z) * 1.4426950408889634f;
    Av2[3] = -expf(Av4.w) * 1.4426950408889634f;
    float aarg[4] = {0.f, 0.f, 0.f, 0.f};
    float Bacc[4] = {0.f, 0.f, 0.f, 0.f};
    __shared__ float Bst[CH][16];
    size_t rowb = (size_t)b * LL + c * CH;
    {
        int j = tid >> 4, col = tid & 15;
        Bst[j][col] = dbc[(rowb + j) * 40 + 8 + col];
    }
    __syncthreads();
    #pragma unroll 4
    for (int j = 0; j < CH; ++j) {
        size_t rr = rowb + j;
        float dtv = dt[rr * 256 + d];
        float xmv = xm[rr * 256 + d];
        float dtxm = dtv * xmv;
        #pragma unroll
        for (int k2 = 0; k2 < 4; ++k2) {
            float arg = dtv * Av2[k2];
            float dA = exp2f(arg);
            Bacc[k2] = Bacc[k2] * dA + Bst[j][sq * 4 + k2] * dtxm;
            aarg[k2] += arg;
        }
    }
    #pragma unroll
    for (int k2 = 0; k2 < 4; ++k2) {
        size_t oo = ((size_t)(blk * 16 + sq * 4 + k2)) * 256 + d;
        Asum[oo] = exp2f(aarg[k2]);
        Bsum[oo] = Bacc[k2];
    }
}

// ---------------- scan mid ----------------
__global__ __launch_bounds__(256) void scan_mid_k(
    const float* __restrict__ Asum, const float* __restrict__ Bsum,
    float* __restrict__ hinit)
{
    int b = blockIdx.x >> 4, s = blockIdx.x & 15;
    int d = threadIdx.x;
    float h = 0.f;
    #pragma unroll 4
    for (int c = 0; c < NCHUNK; ++c) {
        size_t oo = ((size_t)((b * 32 + c) * 16 + s)) * 256 + d;
        hinit[oo] = h;
        h = Asum[oo] * h + Bsum[oo];
    }
}

// ---------------- scan pass 2 + gate + pool ----------------
__global__ __launch_bounds__(1024) void scan2_k(
    const float* __restrict__ dt, const float* __restrict__ xm,
    const float* __restrict__ dbc, const float* __restrict__ A_log,
    const float* __restrict__ hinit, const float* __restrict__ xz,
    const float* __restrict__ dsk, float* __restrict__ part)
{
    int blk = blockIdx.x;
    int c = blk & 31, b = blk >> 5;
    int tid = threadIdx.x;
    int d = tid >> 2, sq = tid & 3;
    float4 Av4 = *(const float4*)(A_log + d * 16 + sq * 4);
    float Av2[4];
    Av2[0] = -expf(Av4.x) * 1.4426950408889634f;
    Av2[1] = -expf(Av4.y) * 1.4426950408889634f;
    Av2[2] = -expf(Av4.z) * 1.4426950408889634f;
    Av2[3] = -expf(Av4.w) * 1.4426950408889634f;
    float hs[4];
    #pragma unroll
    for (int k2 = 0; k2 < 4; ++k2)
        hs[k2] = hinit[((size_t)(blk * 16 + sq * 4 + k2)) * 256 + d];
    float dskv = dsk[d];
    float psum = 0.f;
    __shared__ float Bst[CH][16], Cst[CH][16];
    size_t rowb = (size_t)b * LL + c * CH;
    {
        int j = tid >> 4, col = tid & 15;
        Bst[j][col] = dbc[(rowb + j) * 40 + 8 + col];
        Cst[j][col] = dbc[(rowb + j) * 40 + 24 + col];
    }
    __syncthreads();
    #pragma unroll 2
    for (int j = 0; j < CH; ++j) {
        size_t rr = rowb + j;
        float dtv = dt[rr * 256 + d];
        float xmv = xm[rr * 256 + d];
        float dtxm = dtv * xmv;
        float yv = 0.f;
        #pragma unroll
        for (int k2 = 0; k2 < 4; ++k2) {
            float dA = exp2f(dtv * Av2[k2]);
            hs[k2] = hs[k2] * dA + Bst[j][sq * 4 + k2] * dtxm;
            yv += hs[k2] * Cst[j][sq * 4 + k2];
        }
        yv += __shfl_xor(yv, 1);
        yv += __shfl_xor(yv, 2);
        if (sq == 0) {
            float zv = xz[rr * 512 + 256 + d];
            float sg = zv / (1.f + __expf(-zv));
            psum += (yv + xmv * dskv) * sg;
        }
    }
    if (sq == 0) part[(size_t)blk * 256 + d] = psum;   // part[b][c][d]
}

// ---------------- final: pooled @ out_proj^T -> mlp2 ----------------
__global__ __launch_bounds__(128) void final_k(
    const float* __restrict__ part, const float* __restrict__ opw,
    const float* __restrict__ w1, const float* __restrict__ b1,
    const float* __restrict__ w2, const float* __restrict__ b2,
    float* __restrict__ out)
{
    int b = blockIdx.x, t = threadIdx.x;
    __shared__ float pg[256];
    __shared__ float pooled[128];
    __shared__ float hid[32];
    for (int k = t; k < 256; k += 128) {
        float sm = 0.f;
        #pragma unroll
        for (int c = 0; c < NCHUNK; ++c)
            sm += part[(size_t)(b * 32 + c) * 256 + k];
        pg[k] = sm * (1.f / 2048.f);
    }
    __syncthreads();
    float a = 0.f;
    for (int k = 0; k < 256; ++k) a += pg[k] * opw[(size_t)t * DIN + k];
    pooled[t] = a;
    __syncthreads();
    if (t < 32) {
        float hh = b1[t];
        for (int d2 = 0; d2 < 128; ++d2) hh += pooled[d2] * w1[t * 128 + d2];
        hid[t] = fmaxf(hh, 0.f);
    }
    __syncthreads();
    if (t == 0) {
        float o = b2[0];
        #pragma unroll
        for (int j = 0; j < 32; ++j) o += hid[j] * w2[j];
        out[b] = o;
    }
}

extern "C" void kernel_launch(void* const* d_in, const int* in_sizes, int n_in,
                              void* d_out, int out_size, void* d_ws, size_t ws_size,
                              hipStream_t stream)
{
    const float* x          = (const float*)d_in[0];
    const float* mlp1_w     = (const float*)d_in[1];
    const float* mlp1_b     = (const float*)d_in[2];
    const float* qkv_w      = (const float*)d_in[3];
    const float* qkv_b      = (const float*)d_in[4];
    const float* attn_out_w = (const float*)d_in[5];
    const float* attn_out_b = (const float*)d_in[6];
    const float* ln1_s      = (const float*)d_in[7];
    const float* ln1_b      = (const float*)d_in[8];
    const float* ffw_w1     = (const float*)d_in[9];
    const float* ffw_b1     = (const float*)d_in[10];
    const float* ffw_w2     = (const float*)d_in[11];
    const float* ffw_b2     = (const float*)d_in[12];
    const float* ln2_s      = (const float*)d_in[13];
    const float* ln2_b      = (const float*)d_in[14];
    const float* in_proj_w  = (const float*)d_in[15];
    const float* conv_w     = (const float*)d_in[16];
    const float* conv_b     = (const float*)d_in[17];
    const float* x_proj_w   = (const float*)d_in[18];
    const float* dt_proj_w  = (const float*)d_in[19];
    const float* dt_proj_b  = (const float*)d_in[20];
    const float* A_log      = (const float*)d_in[21];
    const float* D_skip     = (const float*)d_in[22];
    const float* out_proj_w = (const float*)d_in[23];
    const float* mlp2_w1    = (const float*)d_in[24];
    const float* mlp2_b1    = (const float*)d_in[25];
    const float* mlp2_w2    = (const float*)d_in[26];
    const float* mlp2_b2    = (const float*)d_in[27];
    float* out = (float*)d_out;
    float* ws  = (float*)d_ws;

    // workspace layout (floats)
    float* h     = ws;                              // BLROWS*128
    float* xz    = h    + (size_t)BLROWS * DMODEL;  // BLROWS*512  (qkv16 alias)
    float* t1    = xz   + (size_t)BLROWS * 512;     // BLROWS*128 (attn-out bf16 alias / dt)
    float* t2    = t1   + (size_t)BLROWS * DMODEL;  // BLROWS*128 (attn partials / dt hi)
    float* xm    = t2   + (size_t)BLROWS * DMODEL;  // BLROWS*256
    float* dbc   = xm   + (size_t)BLROWS * DIN;     // BLROWS*40
    float* part2 = dbc  + (size_t)BLROWS * 40;      // 8*32*256
    float* Asum  = part2 + 8 * 32 * 256;            // 8*32*16*256
    float* Bsum  = Asum + 8 * 32 * 16 * 256;
    float* hini  = Bsum + 8 * 32 * 16 * 256;
    ushort* w16  = (ushort*)(hini + 8 * 32 * 16 * 256);
    ushort* qkvw16 = w16;                 // 6*384*128 = 294912
    ushort* aow16  = w16 + 294912;        // 98304
    ushort* f1w16  = w16 + 393216;        // 98304
    ushort* f2w16  = w16 + 491520;        // 98304
    ushort* ipw16  = w16 + 589824;        // 65536
    ushort* xpw16  = w16 + 655360;        // 10240
    ushort* qkv16 = (ushort*)xz;
    ushort* t1u   = (ushort*)t1;          // attn out bf16
    float* dtb  = t1;                     // dt (fp32) in mamba phase
    // attn partials overlay the mamba scratch (t2 + first half of xm):
    float* Oprt = t2;                     // 2048*64*32 = 4.19M floats
    float* lprt = t2 + (size_t)2048 * 64 * 32;   // 2048*64

    // weight preconversion
    wcvt_k<<<(294912/4 + 255)/256, 256, 0, stream>>>(qkv_w, qkvw16, 294912/4);
    wcvt_k<<<(98304/4 + 255)/256, 256, 0, stream>>>(attn_out_w, aow16, 98304/4);
    wcvt_k<<<(98304/4 + 255)/256, 256, 0, stream>>>(ffw_w1, f1w16, 98304/4);
    wcvt_k<<<(98304/4 + 255)/256, 256, 0, stream>>>(ffw_w2, f2w16, 98304/4);
    wcvt_k<<<(65536/4 + 255)/256, 256, 0, stream>>>(in_proj_w, ipw16, 65536/4);
    wcvt_k<<<(10240/4 + 255)/256, 256, 0, stream>>>(x_proj_w, xpw16, 10240/4);

    mlp1_pe_k<<<(BLROWS * DMODEL) / 256, 256, 0, stream>>>(x, mlp1_w, mlp1_b, h);

    for (int i = 0; i < NLAYERS; ++i) {
        gemm_qkv_k<<<dim3(3, 256), 256, 0, stream>>>(
            h, qkvw16 + (size_t)i * 384 * 128, qkv_b + i * 384, qkv16);
        attn_part_k<<<2048, 256, 0, stream>>>(qkv16, Oprt, lprt);
        attn_merge_k<<<(BLROWS * DMODEL) / 256, 256, 0, stream>>>(Oprt, lprt, t1u);
        gemm_ln_k<<<256, 256, 0, stream>>>(
            t1u, aow16 + (size_t)i * 128 * 128, attn_out_b + i * 128, h,
            ln1_s + i * 128, ln1_b + i * 128);
        ffw_ln_k<<<256, 256, 0, stream>>>(
            h, f1w16 + (size_t)i * 128 * 128, ffw_b1 + i * 128,
            f2w16 + (size_t)i * 128 * 128, ffw_b2 + i * 128,
            ln2_s + i * 128, ln2_b + i * 128);
    }

    // Mamba block
    gemm_bf16_k<<<dim3(4, 256), 256, 0, stream>>>(h, ipw16, xz, 512);
    conv_silu_k<<<(BLROWS * DIN) / 256, 256, 0, stream>>>(xz, conv_w, conv_b, xm);
    xproj_bf16_k<<<256, 256, 0, stream>>>(xm, xpw16, dbc);
    dtproj_k<<<BLROWS / 4, 256, 0, stream>>>(dbc, dt_proj_w, dt_proj_b, dtb);
    scan1_k<<<256, 1024, 0, stream>>>(dtb, xm, dbc, A_log, Asum, Bsum);
    scan_mid_k<<<128, 256, 0, stream>>>(Asum, Bsum, hini);
    scan2_k<<<256, 1024, 0, stream>>>(dtb, xm, dbc, A_log, hini, xz, D_skip, part2);
    final_k<<<8, 128, 0, stream>>>(part2, out_proj_w, mlp2_w1, mlp2_b1, mlp2_w2, mlp2_b2, out);
}